// Round 14
// baseline (379.468 us; speedup 1.0000x reference)
//
#include <hip/hip_runtime.h>
#include <math.h>

#define NN 50000
#define EE 800000
#define HDIM 96
#define ZDIM 32
#define MAXD 64
#define EBUK 256      // edge buckets (scatter blocks)
#define SB 64         // BN stat buckets
#define BCAP 4096
#define BMUL 5350     // bucket(d) = (d*5350)>>20 ~ d/196, max 255
#define MGRID 782     // CDIV(NN, 64)
#define CDIV(a,b) (((a)+(b)-1)/(b))

typedef unsigned int uint;
typedef unsigned short ushort;
typedef __bf16 bf16x8 __attribute__((ext_vector_type(8)));
typedef float f32x4 __attribute__((ext_vector_type(4)));

// native RNE converts (compiler emits v_cvt_pk_bf16_f32)
__device__ __forceinline__ uint pack2(float a, float b) {
  union { __bf16 h[2]; uint u; } c;
  c.h[0] = (__bf16)a;
  c.h[1] = (__bf16)b;
  return c.u;
}
__device__ __forceinline__ ushort f2b(float f) {
  union { __bf16 h; ushort u; } c;
  c.h = (__bf16)f;
  return c.u;
}
__device__ __forceinline__ float blo(uint u) { return __uint_as_float(u << 16); }
__device__ __forceinline__ float bhi(uint u) { return __uint_as_float(u & 0xffff0000u); }
__device__ __forceinline__ float lrelu(float v) { return v > 0.f ? v : 0.2f * v; }
__device__ __forceinline__ int bukd0(int b) { return (b * 1048576 + 5349) / 5350; }

__device__ __forceinline__ void red_scsh(const float* __restrict__ sb,
                                         const float* __restrict__ g,
                                         const float* __restrict__ b,
                                         float* s_c, float* s_h, int tid) {
  if (tid < 96) {
    float su = 0.f, sq = 0.f;
#pragma unroll 8
    for (int j = 0; j < SB; j++) {
      su += sb[j * 192 + tid];
      sq += sb[j * 192 + 96 + tid];
    }
    float mu = su * (1.0f / NN);
    float va = sq * (1.0f / NN) - mu * mu;
    float sc = g[tid] * rsqrtf(va + 1e-5f);
    s_c[tid] = sc;
    s_h[tid] = fmaf(-sc, mu, b[tid]);
  }
}

// ---------------- prep: Wt_bf slots + folded vectors + zero region ----------------
struct PrepArgs { const float* W[7]; const float* a[7]; };

__global__ void k_prep(PrepArgs p, ushort* __restrict__ wt, float* __restrict__ avb,
                       int* __restrict__ zbase, int zcount) {
  const int SDin[6]  = {256, 96, 96, 32, 96, 96};
  const int SDout[6] = {96, 96, 64, 96, 96, 256};
  const int SL[6]    = {0, 1, 2, 4, 5, 6};
  const int SWoff[6] = {0, 24576, 33792, 39936, 43008, 52224};
  int y = blockIdx.y;
  if (y < 6) {
    int Din = SDin[y], Dout = SDout[y];
    int n = Din * Dout;
    ushort* wo = wt + SWoff[y];
    if (y == 2) {
      const float* W2 = p.W[2];
      const float* W3 = p.W[3];
      for (int o = blockIdx.x * 256 + threadIdx.x; o < n; o += 96 * 256) {
        int c = o / Din, k = o % Din;
        float w = (c < 32) ? W2[(size_t)k * 32 + c] : W3[(size_t)k * 32 + (c - 32)];
        wo[o] = f2b(w);
      }
    } else {
      const float* W = p.W[SL[y]];
      for (int o = blockIdx.x * 256 + threadIdx.x; o < n; o += 96 * 256) {
        int c = o / Din, k = o % Din;
        wo[o] = f2b(W[(size_t)k * Dout + c]);
      }
    }
  } else if (y == 6) {
    int wave = (blockIdx.x * 256 + threadIdx.x) >> 6;
    int lane = threadIdx.x & 63;
    for (int row = wave; row < 128; row += 96 * 4) {
      int l = (row < 32) ? 4 : 6;
      int k = (row < 32) ? row : row - 32;
      int Dout = (l == 4) ? 96 : 256;
      const float* W = p.W[l];
      const float* a = p.a[l];
      float s0 = 0.f, s1 = 0.f;
      for (int c = lane; c < Dout; c += 64) {
        float w = W[(size_t)k * Dout + c];
        s0 = fmaf(w, a[c], s0);
        s1 = fmaf(w, a[Dout + c], s1);
      }
      for (int o = 32; o > 0; o >>= 1) {
        s0 += __shfl_down(s0, o);
        s1 += __shfl_down(s1, o);
      }
      if (lane == 0) {
        if (l == 4) { avb[k] = s0; avb[32 + k] = s1; }
        else { avb[64 + k] = s0; avb[160 + k] = s1; }
      }
    }
  } else {
    for (int i = blockIdx.x * 256 + threadIdx.x; i < zcount; i += 96 * 256)
      zbase[i] = 0;
  }
}

// ---------------- phase A: partition edges into 256 dst-buckets (8 edges/thread) ----------------
__global__ __launch_bounds__(256) void k_partA(const int* __restrict__ eidx,
                                               int* __restrict__ bcnt,
                                               uint* __restrict__ barr) {
  __shared__ int hist[EBUK];
  __shared__ int hbase[EBUK];
  const int tot = EE + NN;
  const int tid = threadIdx.x;
  int base = blockIdx.x * 2048 + tid;
  if (tid < EBUK) hist[tid] = 0;
  __syncthreads();
  int dv[8], sv[8], bk[8], ofs[8];
  bool ok[8];
#pragma unroll
  for (int j = 0; j < 8; j++) {
    int e = base + j * 256;
    ok[j] = e < tot;
    dv[j] = sv[j] = bk[j] = ofs[j] = 0;
    if (ok[j]) {
      if (e < EE) { sv[j] = eidx[e]; dv[j] = eidx[EE + e]; }
      else { sv[j] = dv[j] = e - EE; }
      bk[j] = (dv[j] * BMUL) >> 20;
      ofs[j] = atomicAdd(&hist[bk[j]], 1);
    }
  }
  __syncthreads();
  if (tid < EBUK) hbase[tid] = atomicAdd(&bcnt[tid], hist[tid]);
  __syncthreads();
#pragma unroll
  for (int j = 0; j < 8; j++) {
    if (ok[j]) {
      int w = hbase[bk[j]] + ofs[j];
      if (w < BCAP) barr[bk[j] * BCAP + w] = ((uint)dv[j] << 16) | (uint)sv[j];
    }
  }
}

// ---------------- MFMA bf16 GEMM body (device) ----------------
template<int DIN, int DOUT, int AMODE, bool BF16_OUT, bool ADD_BIAS, int EPI, bool STATS>
__device__ __forceinline__ void mfma_body(
    int bid, const void* __restrict__ A1, const void* __restrict__ A2,
    const float* __restrict__ sbA, const float* __restrict__ gA, const float* __restrict__ bA,
    const float* __restrict__ sbB, const float* __restrict__ gB, const float* __restrict__ bB,
    const ushort* __restrict__ Wt, const float* __restrict__ bias,
    void* __restrict__ outp, const float* __restrict__ aA, const float* __restrict__ aB,
    float* __restrict__ el, float* __restrict__ er,
    float2* __restrict__ elp, float2* __restrict__ erp, float* __restrict__ sbout) {
  constexpr int NT = DOUT / 16;
  constexpr int KS = DIN / 32;
  const int tid = threadIdx.x;
  const int lane = tid & 63;
  const int wv = tid >> 6;
  const int row0 = bid * 64 + wv * 16;
  const int cl = lane & 15;
  const int g = lane >> 4;
  const int arow = min(row0 + cl, NN - 1);
  __shared__ float s_c1[96], s_h1[96], s_c2[96], s_h2[96];
  if constexpr (AMODE >= 2) {
    red_scsh(sbA, gA, bA, s_c1, s_h1, tid);
    if constexpr (AMODE == 3) red_scsh(sbB, gB, bB, s_c2, s_h2, tid);
    __syncthreads();
  }
  f32x4 acc[NT];
#pragma unroll
  for (int t = 0; t < NT; t++) acc[t] = (f32x4){0.f, 0.f, 0.f, 0.f};
#pragma unroll
  for (int ks = 0; ks < KS; ks++) {
    bf16x8 af;
    if constexpr (AMODE == 0) {
      af = *(const bf16x8*)((const ushort*)A1 + (size_t)arow * DIN + ks * 32 + g * 8);
    } else if constexpr (AMODE == 1) {
      const f32x4* Af = (const f32x4*)((const float*)A1 + (size_t)arow * DIN + ks * 32 + g * 8);
      f32x4 lo = __builtin_nontemporal_load(Af);       // x is read exactly once
      f32x4 hi = __builtin_nontemporal_load(Af + 1);
      union { uint4 u; bf16x8 v; } cvt;
      cvt.u.x = pack2(lo[0], lo[1]); cvt.u.y = pack2(lo[2], lo[3]);
      cvt.u.z = pack2(hi[0], hi[1]); cvt.u.w = pack2(hi[2], hi[3]);
      af = cvt.v;
    } else {
      const float* p1 = (const float*)A1 + (size_t)arow * DIN + ks * 32 + g * 8;
      const float* p2 = (const float*)A2 + (size_t)arow * DIN + ks * 32 + g * 8;
      const int f0 = ks * 32 + g * 8;
      float v[8];
#pragma unroll
      for (int j = 0; j < 8; j++) {
        float t = fmaxf(fmaf(s_c1[f0 + j], p1[j], s_h1[f0 + j]), 0.f);
        if constexpr (AMODE == 3)
          t += fmaxf(fmaf(s_c2[f0 + j], p2[j], s_h2[f0 + j]), 0.f);
        v[j] = t;
      }
      union { uint4 u; bf16x8 b8; } cv;
      cv.u.x = pack2(v[0], v[1]); cv.u.y = pack2(v[2], v[3]);
      cv.u.z = pack2(v[4], v[5]); cv.u.w = pack2(v[6], v[7]);
      af = cv.b8;
    }
#pragma unroll
    for (int t = 0; t < NT; t++) {
      bf16x8 bf = *(const bf16x8*)(Wt + (size_t)(t * 16 + cl) * DIN + ks * 32 + g * 8);
      acc[t] = __builtin_amdgcn_mfma_f32_16x16x32_bf16(af, bf, acc[t], 0, 0, 0);
    }
  }
  if constexpr (EPI == 1) {
#pragma unroll
    for (int r = 0; r < 4; r++) {
      float l0 = 0.f, l1 = 0.f;
#pragma unroll
      for (int t = 0; t < NT; t++) {
        float w0 = aA[t * 16 + cl], w1 = aA[DOUT + t * 16 + cl];
        l0 = fmaf(acc[t][r], w0, l0);
        l1 = fmaf(acc[t][r], w1, l1);
      }
#pragma unroll
      for (int m = 1; m < 16; m <<= 1) {
        l0 += __shfl_xor(l0, m);
        l1 += __shfl_xor(l1, m);
      }
      int row = row0 + g * 4 + r;
      if (cl == 0 && row < NN) { el[row] = l0; er[row] = l1; }
    }
  }
  if constexpr (EPI == 2) {
#pragma unroll
    for (int r = 0; r < 4; r++) {
      float m0 = 0.f, m1 = 0.f, v0 = 0.f, v1 = 0.f;
#pragma unroll
      for (int t = 0; t < 2; t++) {
        int c = t * 16 + cl;
        m0 = fmaf(acc[t][r], aA[c], m0);
        m1 = fmaf(acc[t][r], aA[32 + c], m1);
        v0 = fmaf(acc[t + 2][r], aB[c], v0);
        v1 = fmaf(acc[t + 2][r], aB[32 + c], v1);
      }
#pragma unroll
      for (int m = 1; m < 16; m <<= 1) {
        m0 += __shfl_xor(m0, m); m1 += __shfl_xor(m1, m);
        v0 += __shfl_xor(v0, m); v1 += __shfl_xor(v1, m);
      }
      int row = row0 + g * 4 + r;
      if (cl == 0 && row < NN) {
        elp[row] = make_float2(m0, v0);
        erp[row] = make_float2(m1, v1);
      }
    }
  }
  if constexpr (ADD_BIAS) {
#pragma unroll
    for (int t = 0; t < NT; t++) {
      float bv = bias[t * 16 + cl];
#pragma unroll
      for (int r = 0; r < 4; r++) acc[t][r] += bv;
    }
  }
  if constexpr (STATS) {
    __shared__ float s_su[96], s_sq[96];
    if (tid < 96) { s_su[tid] = 0.f; s_sq[tid] = 0.f; }
    __syncthreads();
#pragma unroll
    for (int t = 0; t < NT; t++) {
      float su = 0.f, sq = 0.f;
#pragma unroll
      for (int r = 0; r < 4; r++) {
        if (row0 + g * 4 + r < NN) {
          float v = acc[t][r];
          su += v;
          sq = fmaf(v, v, sq);
        }
      }
      atomicAdd(&s_su[t * 16 + cl], su);
      atomicAdd(&s_sq[t * 16 + cl], sq);
    }
    __syncthreads();
    if (tid < 96) {
      float* bk = sbout + (bid & (SB - 1)) * 192;
      atomicAdd(&bk[tid], s_su[tid]);
      atomicAdd(&bk[96 + tid], s_sq[tid]);
    }
  }
  if constexpr (EPI == 3) {
    float mx[4], sm[4];
#pragma unroll
    for (int r = 0; r < 4; r++) mx[r] = -3.4e38f;
#pragma unroll
    for (int t = 0; t < NT; t++)
#pragma unroll
      for (int r = 0; r < 4; r++) mx[r] = fmaxf(mx[r], acc[t][r]);
#pragma unroll
    for (int r = 0; r < 4; r++) {
#pragma unroll
      for (int msk = 1; msk < 16; msk <<= 1)
        mx[r] = fmaxf(mx[r], __shfl_xor(mx[r], msk));
      sm[r] = 0.f;
    }
#pragma unroll
    for (int t = 0; t < NT; t++)
#pragma unroll
      for (int r = 0; r < 4; r++) { acc[t][r] = expf(acc[t][r] - mx[r]); sm[r] += acc[t][r]; }
#pragma unroll
    for (int r = 0; r < 4; r++) {
#pragma unroll
      for (int msk = 1; msk < 16; msk <<= 1) sm[r] += __shfl_xor(sm[r], msk);
      sm[r] = 1.f / sm[r];
    }
#pragma unroll
    for (int t = 0; t < NT; t++)
#pragma unroll
      for (int r = 0; r < 4; r++) acc[t][r] *= sm[r];
  }
#pragma unroll
  for (int r = 0; r < 4; r++) {
    int grow = row0 + g * 4 + r;
    if (grow >= NN) continue;
    if constexpr (BF16_OUT) {
      ushort* o = (ushort*)outp + (size_t)grow * DOUT + cl;
#pragma unroll
      for (int t = 0; t < NT; t++) o[t * 16] = f2b(acc[t][r]);
    } else {
      float* o = (float*)outp + (size_t)grow * DOUT + cl;
#pragma unroll
      for (int t = 0; t < NT; t++) o[t * 16] = acc[t][r];
    }
  }
}

template<int DIN, int DOUT, int AMODE, bool BF16_OUT, bool ADD_BIAS, int EPI, bool STATS>
__global__ __launch_bounds__(256) void k_mfma(
    const void* __restrict__ A1, const void* __restrict__ A2,
    const float* __restrict__ sbA, const float* __restrict__ gA, const float* __restrict__ bA,
    const float* __restrict__ sbB, const float* __restrict__ gB, const float* __restrict__ bB,
    const ushort* __restrict__ Wt, const float* __restrict__ bias,
    void* __restrict__ outp, const float* __restrict__ aA, const float* __restrict__ aB,
    float* __restrict__ el, float* __restrict__ er,
    float2* __restrict__ elp, float2* __restrict__ erp, float* __restrict__ sbout) {
  mfma_body<DIN, DOUT, AMODE, BF16_OUT, ADD_BIAS, EPI, STATS>(
      blockIdx.x, A1, A2, sbA, gA, bA, sbB, gB, bB, Wt, bias, outp, aA, aB,
      el, er, elp, erp, sbout);
}

// ---------------- fat: 256-bucket scatter (LDS histogram) ∪ enc1 GEMM ----------------
__global__ __launch_bounds__(256) void k_fatB(
    const int* __restrict__ bcnt, const uint* __restrict__ barr,
    int* __restrict__ dcnt, ushort* __restrict__ srcs,
    const float* __restrict__ x, const ushort* __restrict__ Wt,
    ushort* __restrict__ hbf, const float* __restrict__ aA,
    float* __restrict__ el, float* __restrict__ er) {
  if (blockIdx.x < EBUK) {
    const int b = blockIdx.x;
    const int tid = threadIdx.x;
    const int d0 = bukd0(b);
    const int d1 = min(bukd0(b + 1), NN);
    const int width = d1 - d0;           // <= 197
    __shared__ int hist[200];
    for (int t = tid; t < width; t += 256) hist[t] = 0;
    __syncthreads();
    const int n = min(bcnt[b], BCAP);
    const uint* bp = barr + b * BCAP;
    int idx = tid;
    for (; idx + 768 < n; idx += 1024) {
      uint e0 = bp[idx], e1 = bp[idx + 256], e2 = bp[idx + 512], e3 = bp[idx + 768];
      int r0 = (int)(e0 >> 16), r1 = (int)(e1 >> 16);
      int r2 = (int)(e2 >> 16), r3 = (int)(e3 >> 16);
      int p0 = atomicAdd(&hist[r0 - d0], 1);
      int p1 = atomicAdd(&hist[r1 - d0], 1);
      int p2 = atomicAdd(&hist[r2 - d0], 1);
      int p3 = atomicAdd(&hist[r3 - d0], 1);
      if (p0 < MAXD) srcs[r0 * MAXD + p0] = (ushort)(e0 & 0xffffu);
      if (p1 < MAXD) srcs[r1 * MAXD + p1] = (ushort)(e1 & 0xffffu);
      if (p2 < MAXD) srcs[r2 * MAXD + p2] = (ushort)(e2 & 0xffffu);
      if (p3 < MAXD) srcs[r3 * MAXD + p3] = (ushort)(e3 & 0xffffu);
    }
    for (; idx < n; idx += 256) {
      uint e = bp[idx];
      int d = (int)(e >> 16);
      int p = atomicAdd(&hist[d - d0], 1);
      if (p < MAXD) srcs[d * MAXD + p] = (ushort)(e & 0xffffu);
    }
    __syncthreads();
    for (int t = tid; t < width; t += 256) dcnt[d0 + t] = hist[t];
  } else {
    mfma_body<256, 96, 1, true, false, 1, false>(
        blockIdx.x - EBUK, x, nullptr, nullptr, nullptr, nullptr, nullptr, nullptr, nullptr,
        Wt, nullptr, hbf, aA, nullptr, el, er, nullptr, nullptr, nullptr);
  }
}

// ---------------- single-pass GAT aggregation + optional fused BN-stat partials ----------------
template<int D, bool BF16O, bool STATS>
__global__ __launch_bounds__(256) void k_agg1(
    const ushort* __restrict__ hb, const float* __restrict__ el,
    const float* __restrict__ er, const int* __restrict__ dcnt,
    const ushort* __restrict__ srcs, const float* __restrict__ bias,
    void* __restrict__ out, float* __restrict__ sbuck) {
  constexpr int LPN = (D <= 32) ? 32 : 64;
  constexpr int NPB = 256 / LPN;
  constexpr int NU = D / 2;
  const int tid = threadIdx.x;
  const int slot = tid / LPN;
  const int ln = tid % LPN;
  const int i = blockIdx.x * NPB + slot;
  const int beg = i * MAXD;
  const int deg = min(dcnt[i], MAXD);
  const int end = beg + deg;
  const float eri = er[i];
  const uint* h32 = (const uint*)hb;
  __shared__ float s_al[256];
  __shared__ uint s_of[256];
  float v0 = -3.4e38f;
  int sv0 = 0;
  if (ln < deg) { sv0 = srcs[beg + ln]; v0 = lrelu(el[sv0] + eri); }
  float m = v0;
  for (int c = beg + LPN; c < end; c += LPN) {
    int e = c + ln;
    if (e < end) m = fmaxf(m, lrelu(el[srcs[e]] + eri));
  }
  for (int o = LPN / 2; o; o >>= 1) m = fmaxf(m, __shfl_xor(m, o, LPN));
  float s = (ln < deg) ? expf(v0 - m) : 0.f;
  for (int c = beg + LPN; c < end; c += LPN) {
    int e = c + ln;
    if (e < end) s += expf(lrelu(el[srcs[e]] + eri) - m);
  }
  for (int o = LPN / 2; o; o >>= 1) s += __shfl_xor(s, o, LPN);
  const float inv = 1.0f / s;
  float acc0 = 0.f, acc1 = 0.f;
  if (ln < deg) { s_al[tid] = expf(v0 - m) * inv; s_of[tid] = (uint)sv0 * NU; }
  const int base = slot * LPN;
  int nv = min(LPN, deg);
  if (ln < NU) {
    int t = 0;
    for (; t + 8 <= nv; t += 8) {
      uint o0 = s_of[base + t],     o1 = s_of[base + t + 1];
      uint o2 = s_of[base + t + 2], o3 = s_of[base + t + 3];
      uint o4 = s_of[base + t + 4], o5 = s_of[base + t + 5];
      uint o6 = s_of[base + t + 6], o7 = s_of[base + t + 7];
      uint u0 = h32[o0 + ln], u1 = h32[o1 + ln], u2 = h32[o2 + ln], u3 = h32[o3 + ln];
      uint u4 = h32[o4 + ln], u5 = h32[o5 + ln], u6 = h32[o6 + ln], u7 = h32[o7 + ln];
      float a0 = s_al[base + t],     a1 = s_al[base + t + 1];
      float a2 = s_al[base + t + 2], a3 = s_al[base + t + 3];
      float a4 = s_al[base + t + 4], a5 = s_al[base + t + 5];
      float a6 = s_al[base + t + 6], a7 = s_al[base + t + 7];
      acc0 = fmaf(a0, blo(u0), acc0); acc1 = fmaf(a0, bhi(u0), acc1);
      acc0 = fmaf(a1, blo(u1), acc0); acc1 = fmaf(a1, bhi(u1), acc1);
      acc0 = fmaf(a2, blo(u2), acc0); acc1 = fmaf(a2, bhi(u2), acc1);
      acc0 = fmaf(a3, blo(u3), acc0); acc1 = fmaf(a3, bhi(u3), acc1);
      acc0 = fmaf(a4, blo(u4), acc0); acc1 = fmaf(a4, bhi(u4), acc1);
      acc0 = fmaf(a5, blo(u5), acc0); acc1 = fmaf(a5, bhi(u5), acc1);
      acc0 = fmaf(a6, blo(u6), acc0); acc1 = fmaf(a6, bhi(u6), acc1);
      acc0 = fmaf(a7, blo(u7), acc0); acc1 = fmaf(a7, bhi(u7), acc1);
    }
    for (; t + 4 <= nv; t += 4) {
      uint o0 = s_of[base + t],     o1 = s_of[base + t + 1];
      uint o2 = s_of[base + t + 2], o3 = s_of[base + t + 3];
      uint u0 = h32[o0 + ln], u1 = h32[o1 + ln], u2 = h32[o2 + ln], u3 = h32[o3 + ln];
      float a0 = s_al[base + t],     a1 = s_al[base + t + 1];
      float a2 = s_al[base + t + 2], a3 = s_al[base + t + 3];
      acc0 = fmaf(a0, blo(u0), acc0); acc1 = fmaf(a0, bhi(u0), acc1);
      acc0 = fmaf(a1, blo(u1), acc0); acc1 = fmaf(a1, bhi(u1), acc1);
      acc0 = fmaf(a2, blo(u2), acc0); acc1 = fmaf(a2, bhi(u2), acc1);
      acc0 = fmaf(a3, blo(u3), acc0); acc1 = fmaf(a3, bhi(u3), acc1);
    }
    for (; t < nv; t++) {
      float a = s_al[base + t];
      uint u = h32[s_of[base + t] + ln];
      acc0 = fmaf(a, blo(u), acc0);
      acc1 = fmaf(a, bhi(u), acc1);
    }
  }
  for (int c = beg + LPN; c < end; c += LPN) {
    int e = c + ln;
    if (e < end) {
      int sv = srcs[e];
      s_al[tid] = expf(lrelu(el[sv] + eri) - m) * inv;
      s_of[tid] = (uint)sv * NU;
    }
    int nv2 = min(LPN, end - c);
    if (ln < NU) {
      for (int t = 0; t < nv2; t++) {
        float a = s_al[base + t];
        uint u = h32[s_of[base + t] + ln];
        acc0 = fmaf(a, blo(u), acc0);
        acc1 = fmaf(a, bhi(u), acc1);
      }
    }
  }
  float o0 = 0.f, o1 = 0.f;
  if (ln < NU) {
    float b0 = bias ? bias[2 * ln] : 0.f;
    float b1 = bias ? bias[2 * ln + 1] : 0.f;
    o0 = acc0 + b0;
    o1 = acc1 + b1;
    if constexpr (BF16O) {
      ((uint*)out)[(size_t)i * NU + ln] = pack2(o0, o1);
    } else {
      ((float2*)out)[(size_t)i * NU + ln] = make_float2(o0, o1);
    }
  }
  if constexpr (STATS) {
    __shared__ float s_val[4][96];
    if (ln < NU) {
      s_val[slot][2 * ln] = o0;
      s_val[slot][2 * ln + 1] = o1;
    }
    __syncthreads();
    if (tid < 96) {
      float su = 0.f, sq = 0.f;
#pragma unroll
      for (int s2 = 0; s2 < 4; s2++) {
        float v = s_val[s2][tid];
        su += v;
        sq = fmaf(v, v, sq);
      }
      float* bk = sbuck + (blockIdx.x & (SB - 1)) * 192;
      atomicAdd(&bk[tid], su);
      atomicAdd(&bk[96 + tid], sq);
    }
  }
}

// ---------------- fused mu+lv aggregation + rsample + dec1 logits ----------------
__global__ __launch_bounds__(256) void k_aggmulv(
    const ushort* __restrict__ hb, const float2* __restrict__ elp,
    const float2* __restrict__ erp, const int* __restrict__ dcnt,
    const ushort* __restrict__ srcs, const float* __restrict__ bmu,
    const float* __restrict__ blv, float* __restrict__ qm, float* __restrict__ qs,
    const float* __restrict__ eps, float* __restrict__ qz,
    ushort* __restrict__ qzbf, const float* __restrict__ av4,
    float* __restrict__ el, float* __restrict__ er) {
  const int tid = threadIdx.x;
  const int slot = tid >> 5;
  const int ln = tid & 31;
  const int i = blockIdx.x * 8 + slot;
  if (i >= NN) return;
  const int beg = i * MAXD;
  const int deg = min(dcnt[i], MAXD);
  const int end = beg + deg;
  const float2 eri = erp[i];
  const uint* h32 = (const uint*)hb;
  __shared__ float s_am[256];
  __shared__ float s_av[256];
  __shared__ uint s_of[256];
  float v0m = -3.4e38f, v0l = -3.4e38f;
  int sv0 = 0;
  if (ln < deg) {
    sv0 = srcs[beg + ln];
    float2 p = elp[sv0];
    v0m = lrelu(p.x + eri.x);
    v0l = lrelu(p.y + eri.y);
  }
  float mm = v0m, ml = v0l;
  for (int c = beg + 32; c < end; c += 32) {
    int e = c + ln;
    if (e < end) {
      float2 p = elp[srcs[e]];
      mm = fmaxf(mm, lrelu(p.x + eri.x));
      ml = fmaxf(ml, lrelu(p.y + eri.y));
    }
  }
  for (int o = 16; o; o >>= 1) {
    mm = fmaxf(mm, __shfl_xor(mm, o, 32));
    ml = fmaxf(ml, __shfl_xor(ml, o, 32));
  }
  float sm = 0.f, sl = 0.f;
  if (ln < deg) { sm = expf(v0m - mm); sl = expf(v0l - ml); }
  for (int c = beg + 32; c < end; c += 32) {
    int e = c + ln;
    if (e < end) {
      float2 p = elp[srcs[e]];
      sm += expf(lrelu(p.x + eri.x) - mm);
      sl += expf(lrelu(p.y + eri.y) - ml);
    }
  }
  for (int o = 16; o; o >>= 1) {
    sm += __shfl_xor(sm, o, 32);
    sl += __shfl_xor(sl, o, 32);
  }
  const float invm = 1.0f / sm, invl = 1.0f / sl;
  float acc0 = 0.f, acc1 = 0.f;
  if (ln < deg) {
    s_am[tid] = expf(v0m - mm) * invm;
    s_av[tid] = expf(v0l - ml) * invl;
    s_of[tid] = (uint)sv0 * 32;
  }
  const int base = slot * 32;
  const float* s_sel = (ln < 16) ? s_am : s_av;
  int nv = min(32, deg);
  int t = 0;
  for (; t + 4 <= nv; t += 4) {
    uint o0 = s_of[base + t],     o1 = s_of[base + t + 1];
    uint o2 = s_of[base + t + 2], o3 = s_of[base + t + 3];
    uint u0 = h32[o0 + ln], u1 = h32[o1 + ln], u2 = h32[o2 + ln], u3 = h32[o3 + ln];
    float a0 = s_sel[base + t],     a1 = s_sel[base + t + 1];
    float a2 = s_sel[base + t + 2], a3 = s_sel[base + t + 3];
    acc0 = fmaf(a0, blo(u0), acc0); acc1 = fmaf(a0, bhi(u0), acc1);
    acc0 = fmaf(a1, blo(u1), acc0); acc1 = fmaf(a1, bhi(u1), acc1);
    acc0 = fmaf(a2, blo(u2), acc0); acc1 = fmaf(a2, bhi(u2), acc1);
    acc0 = fmaf(a3, blo(u3), acc0); acc1 = fmaf(a3, bhi(u3), acc1);
  }
  for (; t < nv; t++) {
    float a = s_sel[base + t];
    uint u = h32[s_of[base + t] + ln];
    acc0 = fmaf(a, blo(u), acc0);
    acc1 = fmaf(a, bhi(u), acc1);
  }
  for (int c = beg + 32; c < end; c += 32) {
    int e = c + ln;
    if (e < end) {
      int sv = srcs[e];
      float2 p = elp[sv];
      s_am[tid] = expf(lrelu(p.x + eri.x) - mm) * invm;
      s_av[tid] = expf(lrelu(p.y + eri.y) - ml) * invl;
      s_of[tid] = (uint)sv * 32;
    }
    int nv2 = min(32, end - c);
    for (int tt = 0; tt < nv2; tt++) {
      float a = s_sel[base + tt];
      uint u = h32[s_of[base + tt] + ln];
      acc0 = fmaf(a, blo(u), acc0);
      acc1 = fmaf(a, bhi(u), acc1);
    }
  }
  float b0 = (ln < 16) ? bmu[2 * ln] : blv[2 * (ln - 16)];
  float b1 = (ln < 16) ? bmu[2 * ln + 1] : blv[2 * (ln - 16) + 1];
  float o0 = acc0 + b0, o1 = acc1 + b1;
  if (ln < 16) ((float2*)qm)[(size_t)i * 16 + ln] = make_float2(o0, o1);
  else ((float2*)qs)[(size_t)i * 16 + (ln - 16)] = make_float2(o0, o1);
  float q0 = __shfl_xor(o0, 16, 32);
  float q1 = __shfl_xor(o1, 16, 32);
  if (ln < 16) {
    float2 ep = ((const float2*)eps)[(size_t)i * 16 + ln];
    float sp0 = fmaxf(q0, 0.f) + log1pf(expf(-fabsf(q0))) + 1e-6f;
    float sp1 = fmaxf(q1, 0.f) + log1pf(expf(-fabsf(q1))) + 1e-6f;
    float z0 = fmaf(sp0, ep.x, o0);
    float z1 = fmaf(sp1, ep.y, o1);
    ((float2*)qz)[(size_t)i * 16 + ln] = make_float2(z0, z1);
    ((uint*)qzbf)[(size_t)i * 16 + ln] = pack2(z0, z1);
    float d0 = z0 * av4[2 * ln] + z1 * av4[2 * ln + 1];
    float d1 = z0 * av4[32 + 2 * ln] + z1 * av4[32 + 2 * ln + 1];
    for (int o = 8; o; o >>= 1) {
      d0 += __shfl_xor(d0, o, 16);
      d1 += __shfl_xor(d1, o, 16);
    }
    if (ln == 0) { el[i] = d0; er[i] = d1; }
  }
}

// ---------------- final dual-BN (64 rows/block, in-block stat reduce) ----------------
__global__ __launch_bounds__(256) void k_bn_dual(
    const float* __restrict__ xA, const float* __restrict__ sbA,
    const float* __restrict__ gA, const float* __restrict__ bA,
    const float* __restrict__ xB, const float* __restrict__ sbB,
    const float* __restrict__ gB, const float* __restrict__ bB,
    ushort* __restrict__ outbf, const float* __restrict__ av, const float* __restrict__ bv,
    float* __restrict__ el, float* __restrict__ er) {
  __shared__ float cA[96], hA[96], cB[96], hB[96];
  const int tid = threadIdx.x;
  red_scsh(sbA, gA, bA, cA, hA, tid);
  red_scsh(sbB, gB, bB, cB, hB, tid);
  __syncthreads();
  const int wv = tid >> 6;
  const int ln = tid & 63;
  for (int it = 0; it < 16; it++) {
    int w = blockIdx.x * 64 + it * 4 + wv;
    if (w >= NN) return;
    const size_t base = (size_t)w * HDIM;
    float v1 = fmaxf(fmaf(cA[ln], xA[base + ln], hA[ln]), 0.f) +
               fmaxf(fmaf(cB[ln], xB[base + ln], hB[ln]), 0.f);
    float v2 = 0.f;
    if (ln < 32) {
      int f = 64 + ln;
      v2 = fmaxf(fmaf(cA[f], xA[base + f], hA[f]), 0.f) +
           fmaxf(fmaf(cB[f], xB[base + f], hB[f]), 0.f);
    }
    outbf[base + ln] = f2b(v1);
    if (ln < 32) outbf[base + 64 + ln] = f2b(v2);
    float d0 = v1 * av[ln], d1 = v1 * bv[ln];
    if (ln < 32) { d0 = fmaf(v2, av[64 + ln], d0); d1 = fmaf(v2, bv[64 + ln], d1); }
    for (int o = 32; o > 0; o >>= 1) {
      d0 += __shfl_down(d0, o);
      d1 += __shfl_down(d1, o);
    }
    if (ln == 0) { el[w] = d0; er[w] = d1; }
  }
}

extern "C" void kernel_launch(void* const* d_in, const int* in_sizes, int n_in,
                              void* d_out, int out_size, void* d_ws, size_t ws_size,
                              hipStream_t stream) {
  const float* x    = (const float*)d_in[0];
  const int*   eidx = (const int*)d_in[1];
  const float* eps  = (const float*)d_in[2];
  const float *W[7], *Aa[7], *Bb[7];
  for (int l = 0; l < 7; l++) {
    W[l]  = (const float*)d_in[3 + 3 * l];
    Aa[l] = (const float*)d_in[4 + 3 * l];
    Bb[l] = (const float*)d_in[5 + 3 * l];
  }
  const float* bng[4] = {(const float*)d_in[24], (const float*)d_in[26],
                         (const float*)d_in[28], (const float*)d_in[30]};
  const float* bnb[4] = {(const float*)d_in[25], (const float*)d_in[27],
                         (const float*)d_in[29], (const float*)d_in[31]};

  size_t off_b = 0;
  auto alloc = [&](size_t bytes) -> void* {
    void* p = (char*)d_ws + off_b;
    off_b = (off_b + bytes + 255) & ~(size_t)255;
    return p;
  };
  ushort* hbf   = (ushort*)alloc((size_t)NN * HDIM * 2);
  ushort* sh2   = (ushort*)alloc((size_t)NN * HDIM * 2);
  float* bufB   = (float*)alloc((size_t)NN * HDIM * 4);
  float* bufD   = (float*)alloc((size_t)NN * HDIM * 4);
  ushort* qzbf  = (ushort*)alloc((size_t)NN * ZDIM * 2);
  float* el     = (float*)alloc((size_t)NN * 4);
  float* er     = (float*)alloc((size_t)NN * 4);
  float2* elp   = (float2*)alloc((size_t)NN * 8);
  float2* erp   = (float2*)alloc((size_t)NN * 8);
  int* dcnt     = (int*)alloc((size_t)NN * 4);
  const int ZCNT = EBUK + 4 * SB * 192;
  char* zregion = (char*)alloc((size_t)ZCNT * 4);
  int* bcnt     = (int*)zregion;
  float* sb0    = (float*)(bcnt + EBUK);
  float* sb1    = sb0 + SB * 192;
  float* sb2    = sb1 + SB * 192;
  float* sb3    = sb2 + SB * 192;
  ushort* srcs  = (ushort*)alloc((size_t)NN * MAXD * 2);
  uint* barr    = (uint*)alloc((size_t)EBUK * BCAP * 4);
  ushort* wt    = (ushort*)alloc((size_t)76800 * 2);
  float* avb    = (float*)alloc((size_t)256 * 4);
  (void)alloc(65536);

  float* qz    = (float*)d_out;
  float* qm    = qz + (size_t)NN * ZDIM;
  float* qs    = qm + (size_t)NN * ZDIM;
  float* recon = qs + (size_t)NN * ZDIM;

  const int SW[6] = {0, 24576, 33792, 39936, 43008, 52224};
  const float* nf = nullptr;

  PrepArgs pa;
  for (int l = 0; l < 7; l++) { pa.W[l] = W[l]; pa.a[l] = Aa[l]; }
  k_prep<<<dim3(96, 8), 256, 0, stream>>>(pa, wt, avb, bcnt, ZCNT);

  k_partA<<<CDIV(EE + NN, 2048), 256, 0, stream>>>(eidx, bcnt, barr);
  k_fatB<<<EBUK + MGRID, 256, 0, stream>>>(bcnt, barr, dcnt, srcs,
                                           x, wt + SW[0], hbf, Aa[0], el, er);

  k_agg1<96, false, true><<<CDIV(NN, 4), 256, 0, stream>>>(hbf, el, er, dcnt, srcs,
                                                           Bb[0], bufB, sb0);
  k_mfma<96, 96, 2, true, false, 1, false><<<MGRID, 256, 0, stream>>>(
      bufB, nullptr, sb0, bng[0], bnb[0], nf, nf, nf, wt + SW[1], nullptr, hbf,
      Aa[1], nullptr, el, er, nullptr, nullptr, nullptr);
  k_agg1<96, false, true><<<CDIV(NN, 4), 256, 0, stream>>>(hbf, el, er, dcnt, srcs,
                                                           Bb[1], bufD, sb1);
  k_mfma<96, 64, 3, true, false, 2, false><<<MGRID, 256, 0, stream>>>(
      bufD, bufB, sb1, bng[1], bnb[1], sb0, bng[0], bnb[0], wt + SW[2], nullptr, hbf,
      Aa[2], Aa[3], nullptr, nullptr, elp, erp, nullptr);
  k_aggmulv<<<CDIV(NN, 8), 256, 0, stream>>>(hbf, elp, erp, dcnt, srcs, Bb[2], Bb[3],
                                             qm, qs, eps, qz, qzbf, avb, el, er);

  k_agg1<32, true, false><<<CDIV(NN, 8), 256, 0, stream>>>(qzbf, el, er, dcnt, srcs,
                                                           nullptr, hbf, nullptr);
  k_mfma<32, 96, 0, false, true, 0, true><<<MGRID, 256, 0, stream>>>(
      hbf, nullptr, nf, nf, nf, nf, nf, nf, wt + SW[3], Bb[4], bufB,
      nullptr, nullptr, nullptr, nullptr, nullptr, nullptr, sb2);
  k_mfma<96, 96, 2, true, false, 1, false><<<MGRID, 256, 0, stream>>>(
      bufB, nullptr, sb2, bng[2], bnb[2], nf, nf, nf, wt + SW[4], nullptr, hbf,
      Aa[5], nullptr, el, er, nullptr, nullptr, nullptr);
  k_agg1<96, false, true><<<CDIV(NN, 4), 256, 0, stream>>>(hbf, el, er, dcnt, srcs,
                                                           Bb[5], bufD, sb3);
  k_bn_dual<<<MGRID, 256, 0, stream>>>(bufD, sb3, bng[3], bnb[3],
                                       bufB, sb2, bng[2], bnb[2],
                                       sh2, avb + 64, avb + 160, el, er);
  k_agg1<96, true, false><<<CDIV(NN, 4), 256, 0, stream>>>(sh2, el, er, dcnt, srcs,
                                                           nullptr, hbf, nullptr);
  k_mfma<96, 256, 0, false, true, 3, false><<<MGRID, 256, 0, stream>>>(
      hbf, nullptr, nf, nf, nf, nf, nf, nf, wt + SW[5], Bb[6], recon,
      nullptr, nullptr, nullptr, nullptr, nullptr, nullptr, nullptr);
}

// Round 15
// 377.632 us; speedup vs baseline: 1.0049x; 1.0049x over previous
//
#include <hip/hip_runtime.h>
#include <math.h>

#define NN 50000
#define EE 800000
#define HDIM 96
#define ZDIM 32
#define MAXD 64
#define EBUK 256      // edge buckets (scatter blocks)
#define SB 64         // BN stat buckets
#define BCAP 4096
#define BMUL 5350     // bucket(d) = (d*5350)>>20 ~ d/196, max 255
#define MGRID 782     // CDIV(NN, 64)
#define CDIV(a,b) (((a)+(b)-1)/(b))

typedef unsigned int uint;
typedef unsigned short ushort;
typedef __bf16 bf16x8 __attribute__((ext_vector_type(8)));
typedef float f32x4 __attribute__((ext_vector_type(4)));

// native RNE converts (compiler emits v_cvt_pk_bf16_f32)
__device__ __forceinline__ uint pack2(float a, float b) {
  union { __bf16 h[2]; uint u; } c;
  c.h[0] = (__bf16)a;
  c.h[1] = (__bf16)b;
  return c.u;
}
__device__ __forceinline__ ushort f2b(float f) {
  union { __bf16 h; ushort u; } c;
  c.h = (__bf16)f;
  return c.u;
}
__device__ __forceinline__ float blo(uint u) { return __uint_as_float(u << 16); }
__device__ __forceinline__ float bhi(uint u) { return __uint_as_float(u & 0xffff0000u); }
__device__ __forceinline__ float lrelu(float v) { return v > 0.f ? v : 0.2f * v; }
__device__ __forceinline__ int bukd0(int b) { return (b * 1048576 + 5349) / 5350; }

__device__ __forceinline__ void red_scsh(const float* __restrict__ sb,
                                         const float* __restrict__ g,
                                         const float* __restrict__ b,
                                         float* s_c, float* s_h, int tid) {
  if (tid < 96) {
    float su = 0.f, sq = 0.f;
#pragma unroll 8
    for (int j = 0; j < SB; j++) {
      su += sb[j * 192 + tid];
      sq += sb[j * 192 + 96 + tid];
    }
    float mu = su * (1.0f / NN);
    float va = sq * (1.0f / NN) - mu * mu;
    float sc = g[tid] * rsqrtf(va + 1e-5f);
    s_c[tid] = sc;
    s_h[tid] = fmaf(-sc, mu, b[tid]);
  }
}

// ---------------- prep: Wt_bf slots + folded vectors + zero region ----------------
struct PrepArgs { const float* W[7]; const float* a[7]; };

__global__ void k_prep(PrepArgs p, ushort* __restrict__ wt, float* __restrict__ avb,
                       int* __restrict__ zbase, int zcount) {
  const int SDin[6]  = {256, 96, 96, 32, 96, 96};
  const int SDout[6] = {96, 96, 64, 96, 96, 256};
  const int SL[6]    = {0, 1, 2, 4, 5, 6};
  const int SWoff[6] = {0, 24576, 33792, 39936, 43008, 52224};
  int y = blockIdx.y;
  if (y < 6) {
    int Din = SDin[y], Dout = SDout[y];
    int n = Din * Dout;
    ushort* wo = wt + SWoff[y];
    if (y == 2) {
      const float* W2 = p.W[2];
      const float* W3 = p.W[3];
      for (int o = blockIdx.x * 256 + threadIdx.x; o < n; o += 96 * 256) {
        int c = o / Din, k = o % Din;
        float w = (c < 32) ? W2[(size_t)k * 32 + c] : W3[(size_t)k * 32 + (c - 32)];
        wo[o] = f2b(w);
      }
    } else {
      const float* W = p.W[SL[y]];
      for (int o = blockIdx.x * 256 + threadIdx.x; o < n; o += 96 * 256) {
        int c = o / Din, k = o % Din;
        wo[o] = f2b(W[(size_t)k * Dout + c]);
      }
    }
  } else if (y == 6) {
    int wave = (blockIdx.x * 256 + threadIdx.x) >> 6;
    int lane = threadIdx.x & 63;
    for (int row = wave; row < 128; row += 96 * 4) {
      int l = (row < 32) ? 4 : 6;
      int k = (row < 32) ? row : row - 32;
      int Dout = (l == 4) ? 96 : 256;
      const float* W = p.W[l];
      const float* a = p.a[l];
      float s0 = 0.f, s1 = 0.f;
      for (int c = lane; c < Dout; c += 64) {
        float w = W[(size_t)k * Dout + c];
        s0 = fmaf(w, a[c], s0);
        s1 = fmaf(w, a[Dout + c], s1);
      }
      for (int o = 32; o > 0; o >>= 1) {
        s0 += __shfl_down(s0, o);
        s1 += __shfl_down(s1, o);
      }
      if (lane == 0) {
        if (l == 4) { avb[k] = s0; avb[32 + k] = s1; }
        else { avb[64 + k] = s0; avb[160 + k] = s1; }
      }
    }
  } else {
    for (int i = blockIdx.x * 256 + threadIdx.x; i < zcount; i += 96 * 256)
      zbase[i] = 0;
  }
}

// ---------------- phase A: partition edges into 256 dst-buckets (8 edges/thread) ----------------
__global__ __launch_bounds__(256) void k_partA(const int* __restrict__ eidx,
                                               int* __restrict__ bcnt,
                                               uint* __restrict__ barr) {
  __shared__ int hist[EBUK];
  __shared__ int hbase[EBUK];
  const int tot = EE + NN;
  const int tid = threadIdx.x;
  int base = blockIdx.x * 2048 + tid;
  if (tid < EBUK) hist[tid] = 0;
  __syncthreads();
  int dv[8], sv[8], bk[8], ofs[8];
  bool ok[8];
#pragma unroll
  for (int j = 0; j < 8; j++) {
    int e = base + j * 256;
    ok[j] = e < tot;
    dv[j] = sv[j] = bk[j] = ofs[j] = 0;
    if (ok[j]) {
      if (e < EE) { sv[j] = eidx[e]; dv[j] = eidx[EE + e]; }
      else { sv[j] = dv[j] = e - EE; }
      bk[j] = (dv[j] * BMUL) >> 20;
      ofs[j] = atomicAdd(&hist[bk[j]], 1);
    }
  }
  __syncthreads();
  if (tid < EBUK) hbase[tid] = atomicAdd(&bcnt[tid], hist[tid]);
  __syncthreads();
#pragma unroll
  for (int j = 0; j < 8; j++) {
    if (ok[j]) {
      int w = hbase[bk[j]] + ofs[j];
      if (w < BCAP) barr[bk[j] * BCAP + w] = ((uint)dv[j] << 16) | (uint)sv[j];
    }
  }
}

// ---------------- MFMA bf16 GEMM body (device) ----------------
template<int DIN, int DOUT, int AMODE, bool BF16_OUT, bool ADD_BIAS, int EPI, bool STATS>
__device__ __forceinline__ void mfma_body(
    int bid, const void* __restrict__ A1, const void* __restrict__ A2,
    const float* __restrict__ sbA, const float* __restrict__ gA, const float* __restrict__ bA,
    const float* __restrict__ sbB, const float* __restrict__ gB, const float* __restrict__ bB,
    const ushort* __restrict__ Wt, const float* __restrict__ bias,
    void* __restrict__ outp, const float* __restrict__ aA, const float* __restrict__ aB,
    float* __restrict__ el, float* __restrict__ er,
    float2* __restrict__ elp, float2* __restrict__ erp, float* __restrict__ sbout) {
  constexpr int NT = DOUT / 16;
  constexpr int KS = DIN / 32;
  const int tid = threadIdx.x;
  const int lane = tid & 63;
  const int wv = tid >> 6;
  const int row0 = bid * 64 + wv * 16;
  const int cl = lane & 15;
  const int g = lane >> 4;
  const int arow = min(row0 + cl, NN - 1);
  __shared__ float s_c1[96], s_h1[96], s_c2[96], s_h2[96];
  if constexpr (AMODE >= 2) {
    red_scsh(sbA, gA, bA, s_c1, s_h1, tid);
    if constexpr (AMODE == 3) red_scsh(sbB, gB, bB, s_c2, s_h2, tid);
    __syncthreads();
  }
  f32x4 acc[NT];
#pragma unroll
  for (int t = 0; t < NT; t++) acc[t] = (f32x4){0.f, 0.f, 0.f, 0.f};
#pragma unroll
  for (int ks = 0; ks < KS; ks++) {
    bf16x8 af;
    if constexpr (AMODE == 0) {
      af = *(const bf16x8*)((const ushort*)A1 + (size_t)arow * DIN + ks * 32 + g * 8);
    } else if constexpr (AMODE == 1) {
      const f32x4* Af = (const f32x4*)((const float*)A1 + (size_t)arow * DIN + ks * 32 + g * 8);
      f32x4 lo = __builtin_nontemporal_load(Af);       // x is read exactly once
      f32x4 hi = __builtin_nontemporal_load(Af + 1);
      union { uint4 u; bf16x8 v; } cvt;
      cvt.u.x = pack2(lo[0], lo[1]); cvt.u.y = pack2(lo[2], lo[3]);
      cvt.u.z = pack2(hi[0], hi[1]); cvt.u.w = pack2(hi[2], hi[3]);
      af = cvt.v;
    } else {
      const float* p1 = (const float*)A1 + (size_t)arow * DIN + ks * 32 + g * 8;
      const float* p2 = (const float*)A2 + (size_t)arow * DIN + ks * 32 + g * 8;
      const int f0 = ks * 32 + g * 8;
      float v[8];
#pragma unroll
      for (int j = 0; j < 8; j++) {
        float t = fmaxf(fmaf(s_c1[f0 + j], p1[j], s_h1[f0 + j]), 0.f);
        if constexpr (AMODE == 3)
          t += fmaxf(fmaf(s_c2[f0 + j], p2[j], s_h2[f0 + j]), 0.f);
        v[j] = t;
      }
      union { uint4 u; bf16x8 b8; } cv;
      cv.u.x = pack2(v[0], v[1]); cv.u.y = pack2(v[2], v[3]);
      cv.u.z = pack2(v[4], v[5]); cv.u.w = pack2(v[6], v[7]);
      af = cv.b8;
    }
#pragma unroll
    for (int t = 0; t < NT; t++) {
      bf16x8 bf = *(const bf16x8*)(Wt + (size_t)(t * 16 + cl) * DIN + ks * 32 + g * 8);
      acc[t] = __builtin_amdgcn_mfma_f32_16x16x32_bf16(af, bf, acc[t], 0, 0, 0);
    }
  }
  if constexpr (EPI == 1) {
#pragma unroll
    for (int r = 0; r < 4; r++) {
      float l0 = 0.f, l1 = 0.f;
#pragma unroll
      for (int t = 0; t < NT; t++) {
        float w0 = aA[t * 16 + cl], w1 = aA[DOUT + t * 16 + cl];
        l0 = fmaf(acc[t][r], w0, l0);
        l1 = fmaf(acc[t][r], w1, l1);
      }
#pragma unroll
      for (int m = 1; m < 16; m <<= 1) {
        l0 += __shfl_xor(l0, m);
        l1 += __shfl_xor(l1, m);
      }
      int row = row0 + g * 4 + r;
      if (cl == 0 && row < NN) { el[row] = l0; er[row] = l1; }
    }
  }
  if constexpr (EPI == 2) {
#pragma unroll
    for (int r = 0; r < 4; r++) {
      float m0 = 0.f, m1 = 0.f, v0 = 0.f, v1 = 0.f;
#pragma unroll
      for (int t = 0; t < 2; t++) {
        int c = t * 16 + cl;
        m0 = fmaf(acc[t][r], aA[c], m0);
        m1 = fmaf(acc[t][r], aA[32 + c], m1);
        v0 = fmaf(acc[t + 2][r], aB[c], v0);
        v1 = fmaf(acc[t + 2][r], aB[32 + c], v1);
      }
#pragma unroll
      for (int m = 1; m < 16; m <<= 1) {
        m0 += __shfl_xor(m0, m); m1 += __shfl_xor(m1, m);
        v0 += __shfl_xor(v0, m); v1 += __shfl_xor(v1, m);
      }
      int row = row0 + g * 4 + r;
      if (cl == 0 && row < NN) {
        elp[row] = make_float2(m0, v0);
        erp[row] = make_float2(m1, v1);
      }
    }
  }
  if constexpr (ADD_BIAS) {
#pragma unroll
    for (int t = 0; t < NT; t++) {
      float bv = bias[t * 16 + cl];
#pragma unroll
      for (int r = 0; r < 4; r++) acc[t][r] += bv;
    }
  }
  if constexpr (STATS) {
    __shared__ float s_su[96], s_sq[96];
    if (tid < 96) { s_su[tid] = 0.f; s_sq[tid] = 0.f; }
    __syncthreads();
#pragma unroll
    for (int t = 0; t < NT; t++) {
      float su = 0.f, sq = 0.f;
#pragma unroll
      for (int r = 0; r < 4; r++) {
        if (row0 + g * 4 + r < NN) {
          float v = acc[t][r];
          su += v;
          sq = fmaf(v, v, sq);
        }
      }
      atomicAdd(&s_su[t * 16 + cl], su);
      atomicAdd(&s_sq[t * 16 + cl], sq);
    }
    __syncthreads();
    if (tid < 96) {
      float* bk = sbout + (bid & (SB - 1)) * 192;
      atomicAdd(&bk[tid], s_su[tid]);
      atomicAdd(&bk[96 + tid], s_sq[tid]);
    }
  }
  if constexpr (EPI == 3) {
    float mx[4], sm[4];
#pragma unroll
    for (int r = 0; r < 4; r++) mx[r] = -3.4e38f;
#pragma unroll
    for (int t = 0; t < NT; t++)
#pragma unroll
      for (int r = 0; r < 4; r++) mx[r] = fmaxf(mx[r], acc[t][r]);
#pragma unroll
    for (int r = 0; r < 4; r++) {
#pragma unroll
      for (int msk = 1; msk < 16; msk <<= 1)
        mx[r] = fmaxf(mx[r], __shfl_xor(mx[r], msk));
      sm[r] = 0.f;
    }
#pragma unroll
    for (int t = 0; t < NT; t++)
#pragma unroll
      for (int r = 0; r < 4; r++) { acc[t][r] = expf(acc[t][r] - mx[r]); sm[r] += acc[t][r]; }
#pragma unroll
    for (int r = 0; r < 4; r++) {
#pragma unroll
      for (int msk = 1; msk < 16; msk <<= 1) sm[r] += __shfl_xor(sm[r], msk);
      sm[r] = 1.f / sm[r];
    }
#pragma unroll
    for (int t = 0; t < NT; t++)
#pragma unroll
      for (int r = 0; r < 4; r++) acc[t][r] *= sm[r];
  }
#pragma unroll
  for (int r = 0; r < 4; r++) {
    int grow = row0 + g * 4 + r;
    if (grow >= NN) continue;
    if constexpr (BF16_OUT) {
      ushort* o = (ushort*)outp + (size_t)grow * DOUT + cl;
#pragma unroll
      for (int t = 0; t < NT; t++) o[t * 16] = f2b(acc[t][r]);
    } else {
      float* o = (float*)outp + (size_t)grow * DOUT + cl;
#pragma unroll
      for (int t = 0; t < NT; t++) o[t * 16] = acc[t][r];
    }
  }
}

template<int DIN, int DOUT, int AMODE, bool BF16_OUT, bool ADD_BIAS, int EPI, bool STATS>
__global__ __launch_bounds__(256) void k_mfma(
    const void* __restrict__ A1, const void* __restrict__ A2,
    const float* __restrict__ sbA, const float* __restrict__ gA, const float* __restrict__ bA,
    const float* __restrict__ sbB, const float* __restrict__ gB, const float* __restrict__ bB,
    const ushort* __restrict__ Wt, const float* __restrict__ bias,
    void* __restrict__ outp, const float* __restrict__ aA, const float* __restrict__ aB,
    float* __restrict__ el, float* __restrict__ er,
    float2* __restrict__ elp, float2* __restrict__ erp, float* __restrict__ sbout) {
  mfma_body<DIN, DOUT, AMODE, BF16_OUT, ADD_BIAS, EPI, STATS>(
      blockIdx.x, A1, A2, sbA, gA, bA, sbB, gB, bB, Wt, bias, outp, aA, aB,
      el, er, elp, erp, sbout);
}

// ---------------- fat: LDS-staged bucket scatter (coalesced copy-out) ∪ enc1 GEMM ----------------
__global__ __launch_bounds__(256) void k_fatB(
    const int* __restrict__ bcnt, const uint* __restrict__ barr,
    int* __restrict__ dcnt, ushort* __restrict__ srcs,
    const float* __restrict__ x, const ushort* __restrict__ Wt,
    ushort* __restrict__ hbf, const float* __restrict__ aA,
    float* __restrict__ el, float* __restrict__ er) {
  if (blockIdx.x < EBUK) {
    const int b = blockIdx.x;
    const int tid = threadIdx.x;
    const int d0 = bukd0(b);
    const int d1 = min(bukd0(b + 1), NN);
    const int width = d1 - d0;           // <= 197
    __shared__ int hist[200];
    __shared__ ushort lsrc[197 * MAXD];  // 25.2 KB bucket-local CSR window
    for (int t = tid; t < width; t += 256) hist[t] = 0;
    __syncthreads();
    const int n = min(bcnt[b], BCAP);
    const uint* bp = barr + b * BCAP;
    int idx = tid;
    for (; idx + 768 < n; idx += 1024) {  // 4 independent edges per iter
      uint e0 = bp[idx], e1 = bp[idx + 256], e2 = bp[idx + 512], e3 = bp[idx + 768];
      int r0 = (int)(e0 >> 16) - d0, r1 = (int)(e1 >> 16) - d0;
      int r2 = (int)(e2 >> 16) - d0, r3 = (int)(e3 >> 16) - d0;
      int p0 = atomicAdd(&hist[r0], 1);
      int p1 = atomicAdd(&hist[r1], 1);
      int p2 = atomicAdd(&hist[r2], 1);
      int p3 = atomicAdd(&hist[r3], 1);
      if (p0 < MAXD) lsrc[r0 * MAXD + p0] = (ushort)(e0 & 0xffffu);
      if (p1 < MAXD) lsrc[r1 * MAXD + p1] = (ushort)(e1 & 0xffffu);
      if (p2 < MAXD) lsrc[r2 * MAXD + p2] = (ushort)(e2 & 0xffffu);
      if (p3 < MAXD) lsrc[r3 * MAXD + p3] = (ushort)(e3 & 0xffffu);
    }
    for (; idx < n; idx += 256) {
      uint e = bp[idx];
      int r = (int)(e >> 16) - d0;
      int p = atomicAdd(&hist[r], 1);
      if (p < MAXD) lsrc[r * MAXD + p] = (ushort)(e & 0xffffu);
    }
    __syncthreads();
    // coalesced copy-out: 128B-aligned window (d0*MAXD*2 bytes), uint4 stores.
    // unused slots carry garbage — harmless, dcnt caps all reads.
    const int nu4 = width * (MAXD / 8);       // uint4 count
    uint4* dst4 = (uint4*)(srcs + (size_t)d0 * MAXD);
    const uint4* src4 = (const uint4*)lsrc;
    for (int t = tid; t < nu4; t += 256) dst4[t] = src4[t];
    for (int t = tid; t < width; t += 256) dcnt[d0 + t] = hist[t];
  } else {
    mfma_body<256, 96, 1, true, false, 1, false>(
        blockIdx.x - EBUK, x, nullptr, nullptr, nullptr, nullptr, nullptr, nullptr, nullptr,
        Wt, nullptr, hbf, aA, nullptr, el, er, nullptr, nullptr, nullptr);
  }
}

// ---------------- single-pass GAT aggregation + optional fused BN-stat partials ----------------
template<int D, bool BF16O, bool STATS>
__global__ __launch_bounds__(256) void k_agg1(
    const ushort* __restrict__ hb, const float* __restrict__ el,
    const float* __restrict__ er, const int* __restrict__ dcnt,
    const ushort* __restrict__ srcs, const float* __restrict__ bias,
    void* __restrict__ out, float* __restrict__ sbuck) {
  constexpr int LPN = (D <= 32) ? 32 : 64;
  constexpr int NPB = 256 / LPN;
  constexpr int NU = D / 2;
  const int tid = threadIdx.x;
  const int slot = tid / LPN;
  const int ln = tid % LPN;
  const int i = blockIdx.x * NPB + slot;
  const int beg = i * MAXD;
  const int deg = min(dcnt[i], MAXD);
  const int end = beg + deg;
  const float eri = er[i];
  const uint* h32 = (const uint*)hb;
  __shared__ float s_al[256];
  __shared__ uint s_of[256];
  float v0 = -3.4e38f;
  int sv0 = 0;
  if (ln < deg) { sv0 = srcs[beg + ln]; v0 = lrelu(el[sv0] + eri); }
  float m = v0;
  for (int c = beg + LPN; c < end; c += LPN) {
    int e = c + ln;
    if (e < end) m = fmaxf(m, lrelu(el[srcs[e]] + eri));
  }
  for (int o = LPN / 2; o; o >>= 1) m = fmaxf(m, __shfl_xor(m, o, LPN));
  float s = (ln < deg) ? expf(v0 - m) : 0.f;
  for (int c = beg + LPN; c < end; c += LPN) {
    int e = c + ln;
    if (e < end) s += expf(lrelu(el[srcs[e]] + eri) - m);
  }
  for (int o = LPN / 2; o; o >>= 1) s += __shfl_xor(s, o, LPN);
  const float inv = 1.0f / s;
  float acc0 = 0.f, acc1 = 0.f;
  if (ln < deg) { s_al[tid] = expf(v0 - m) * inv; s_of[tid] = (uint)sv0 * NU; }
  const int base = slot * LPN;
  int nv = min(LPN, deg);
  if (ln < NU) {
    int t = 0;
    for (; t + 8 <= nv; t += 8) {
      uint o0 = s_of[base + t],     o1 = s_of[base + t + 1];
      uint o2 = s_of[base + t + 2], o3 = s_of[base + t + 3];
      uint o4 = s_of[base + t + 4], o5 = s_of[base + t + 5];
      uint o6 = s_of[base + t + 6], o7 = s_of[base + t + 7];
      uint u0 = h32[o0 + ln], u1 = h32[o1 + ln], u2 = h32[o2 + ln], u3 = h32[o3 + ln];
      uint u4 = h32[o4 + ln], u5 = h32[o5 + ln], u6 = h32[o6 + ln], u7 = h32[o7 + ln];
      float a0 = s_al[base + t],     a1 = s_al[base + t + 1];
      float a2 = s_al[base + t + 2], a3 = s_al[base + t + 3];
      float a4 = s_al[base + t + 4], a5 = s_al[base + t + 5];
      float a6 = s_al[base + t + 6], a7 = s_al[base + t + 7];
      acc0 = fmaf(a0, blo(u0), acc0); acc1 = fmaf(a0, bhi(u0), acc1);
      acc0 = fmaf(a1, blo(u1), acc0); acc1 = fmaf(a1, bhi(u1), acc1);
      acc0 = fmaf(a2, blo(u2), acc0); acc1 = fmaf(a2, bhi(u2), acc1);
      acc0 = fmaf(a3, blo(u3), acc0); acc1 = fmaf(a3, bhi(u3), acc1);
      acc0 = fmaf(a4, blo(u4), acc0); acc1 = fmaf(a4, bhi(u4), acc1);
      acc0 = fmaf(a5, blo(u5), acc0); acc1 = fmaf(a5, bhi(u5), acc1);
      acc0 = fmaf(a6, blo(u6), acc0); acc1 = fmaf(a6, bhi(u6), acc1);
      acc0 = fmaf(a7, blo(u7), acc0); acc1 = fmaf(a7, bhi(u7), acc1);
    }
    for (; t + 4 <= nv; t += 4) {
      uint o0 = s_of[base + t],     o1 = s_of[base + t + 1];
      uint o2 = s_of[base + t + 2], o3 = s_of[base + t + 3];
      uint u0 = h32[o0 + ln], u1 = h32[o1 + ln], u2 = h32[o2 + ln], u3 = h32[o3 + ln];
      float a0 = s_al[base + t],     a1 = s_al[base + t + 1];
      float a2 = s_al[base + t + 2], a3 = s_al[base + t + 3];
      acc0 = fmaf(a0, blo(u0), acc0); acc1 = fmaf(a0, bhi(u0), acc1);
      acc0 = fmaf(a1, blo(u1), acc0); acc1 = fmaf(a1, bhi(u1), acc1);
      acc0 = fmaf(a2, blo(u2), acc0); acc1 = fmaf(a2, bhi(u2), acc1);
      acc0 = fmaf(a3, blo(u3), acc0); acc1 = fmaf(a3, bhi(u3), acc1);
    }
    for (; t < nv; t++) {
      float a = s_al[base + t];
      uint u = h32[s_of[base + t] + ln];
      acc0 = fmaf(a, blo(u), acc0);
      acc1 = fmaf(a, bhi(u), acc1);
    }
  }
  for (int c = beg + LPN; c < end; c += LPN) {
    int e = c + ln;
    if (e < end) {
      int sv = srcs[e];
      s_al[tid] = expf(lrelu(el[sv] + eri) - m) * inv;
      s_of[tid] = (uint)sv * NU;
    }
    int nv2 = min(LPN, end - c);
    if (ln < NU) {
      for (int t = 0; t < nv2; t++) {
        float a = s_al[base + t];
        uint u = h32[s_of[base + t] + ln];
        acc0 = fmaf(a, blo(u), acc0);
        acc1 = fmaf(a, bhi(u), acc1);
      }
    }
  }
  float o0 = 0.f, o1 = 0.f;
  if (ln < NU) {
    float b0 = bias ? bias[2 * ln] : 0.f;
    float b1 = bias ? bias[2 * ln + 1] : 0.f;
    o0 = acc0 + b0;
    o1 = acc1 + b1;
    if constexpr (BF16O) {
      ((uint*)out)[(size_t)i * NU + ln] = pack2(o0, o1);
    } else {
      ((float2*)out)[(size_t)i * NU + ln] = make_float2(o0, o1);
    }
  }
  if constexpr (STATS) {
    __shared__ float s_val[4][96];
    if (ln < NU) {
      s_val[slot][2 * ln] = o0;
      s_val[slot][2 * ln + 1] = o1;
    }
    __syncthreads();
    if (tid < 96) {
      float su = 0.f, sq = 0.f;
#pragma unroll
      for (int s2 = 0; s2 < 4; s2++) {
        float v = s_val[s2][tid];
        su += v;
        sq = fmaf(v, v, sq);
      }
      float* bk = sbuck + (blockIdx.x & (SB - 1)) * 192;
      atomicAdd(&bk[tid], su);
      atomicAdd(&bk[96 + tid], sq);
    }
  }
}

// ---------------- fused mu+lv aggregation + rsample + dec1 logits ----------------
__global__ __launch_bounds__(256) void k_aggmulv(
    const ushort* __restrict__ hb, const float2* __restrict__ elp,
    const float2* __restrict__ erp, const int* __restrict__ dcnt,
    const ushort* __restrict__ srcs, const float* __restrict__ bmu,
    const float* __restrict__ blv, float* __restrict__ qm, float* __restrict__ qs,
    const float* __restrict__ eps, float* __restrict__ qz,
    ushort* __restrict__ qzbf, const float* __restrict__ av4,
    float* __restrict__ el, float* __restrict__ er) {
  const int tid = threadIdx.x;
  const int slot = tid >> 5;
  const int ln = tid & 31;
  const int i = blockIdx.x * 8 + slot;
  if (i >= NN) return;
  const int beg = i * MAXD;
  const int deg = min(dcnt[i], MAXD);
  const int end = beg + deg;
  const float2 eri = erp[i];
  const uint* h32 = (const uint*)hb;
  __shared__ float s_am[256];
  __shared__ float s_av[256];
  __shared__ uint s_of[256];
  float v0m = -3.4e38f, v0l = -3.4e38f;
  int sv0 = 0;
  if (ln < deg) {
    sv0 = srcs[beg + ln];
    float2 p = elp[sv0];
    v0m = lrelu(p.x + eri.x);
    v0l = lrelu(p.y + eri.y);
  }
  float mm = v0m, ml = v0l;
  for (int c = beg + 32; c < end; c += 32) {
    int e = c + ln;
    if (e < end) {
      float2 p = elp[srcs[e]];
      mm = fmaxf(mm, lrelu(p.x + eri.x));
      ml = fmaxf(ml, lrelu(p.y + eri.y));
    }
  }
  for (int o = 16; o; o >>= 1) {
    mm = fmaxf(mm, __shfl_xor(mm, o, 32));
    ml = fmaxf(ml, __shfl_xor(ml, o, 32));
  }
  float sm = 0.f, sl = 0.f;
  if (ln < deg) { sm = expf(v0m - mm); sl = expf(v0l - ml); }
  for (int c = beg + 32; c < end; c += 32) {
    int e = c + ln;
    if (e < end) {
      float2 p = elp[srcs[e]];
      sm += expf(lrelu(p.x + eri.x) - mm);
      sl += expf(lrelu(p.y + eri.y) - ml);
    }
  }
  for (int o = 16; o; o >>= 1) {
    sm += __shfl_xor(sm, o, 32);
    sl += __shfl_xor(sl, o, 32);
  }
  const float invm = 1.0f / sm, invl = 1.0f / sl;
  float acc0 = 0.f, acc1 = 0.f;
  if (ln < deg) {
    s_am[tid] = expf(v0m - mm) * invm;
    s_av[tid] = expf(v0l - ml) * invl;
    s_of[tid] = (uint)sv0 * 32;
  }
  const int base = slot * 32;
  const float* s_sel = (ln < 16) ? s_am : s_av;
  int nv = min(32, deg);
  int t = 0;
  for (; t + 4 <= nv; t += 4) {
    uint o0 = s_of[base + t],     o1 = s_of[base + t + 1];
    uint o2 = s_of[base + t + 2], o3 = s_of[base + t + 3];
    uint u0 = h32[o0 + ln], u1 = h32[o1 + ln], u2 = h32[o2 + ln], u3 = h32[o3 + ln];
    float a0 = s_sel[base + t],     a1 = s_sel[base + t + 1];
    float a2 = s_sel[base + t + 2], a3 = s_sel[base + t + 3];
    acc0 = fmaf(a0, blo(u0), acc0); acc1 = fmaf(a0, bhi(u0), acc1);
    acc0 = fmaf(a1, blo(u1), acc0); acc1 = fmaf(a1, bhi(u1), acc1);
    acc0 = fmaf(a2, blo(u2), acc0); acc1 = fmaf(a2, bhi(u2), acc1);
    acc0 = fmaf(a3, blo(u3), acc0); acc1 = fmaf(a3, bhi(u3), acc1);
  }
  for (; t < nv; t++) {
    float a = s_sel[base + t];
    uint u = h32[s_of[base + t] + ln];
    acc0 = fmaf(a, blo(u), acc0);
    acc1 = fmaf(a, bhi(u), acc1);
  }
  for (int c = beg + 32; c < end; c += 32) {
    int e = c + ln;
    if (e < end) {
      int sv = srcs[e];
      float2 p = elp[sv];
      s_am[tid] = expf(lrelu(p.x + eri.x) - mm) * invm;
      s_av[tid] = expf(lrelu(p.y + eri.y) - ml) * invl;
      s_of[tid] = (uint)sv * 32;
    }
    int nv2 = min(32, end - c);
    for (int tt = 0; tt < nv2; tt++) {
      float a = s_sel[base + tt];
      uint u = h32[s_of[base + tt] + ln];
      acc0 = fmaf(a, blo(u), acc0);
      acc1 = fmaf(a, bhi(u), acc1);
    }
  }
  float b0 = (ln < 16) ? bmu[2 * ln] : blv[2 * (ln - 16)];
  float b1 = (ln < 16) ? bmu[2 * ln + 1] : blv[2 * (ln - 16) + 1];
  float o0 = acc0 + b0, o1 = acc1 + b1;
  if (ln < 16) ((float2*)qm)[(size_t)i * 16 + ln] = make_float2(o0, o1);
  else ((float2*)qs)[(size_t)i * 16 + (ln - 16)] = make_float2(o0, o1);
  float q0 = __shfl_xor(o0, 16, 32);
  float q1 = __shfl_xor(o1, 16, 32);
  if (ln < 16) {
    float2 ep = ((const float2*)eps)[(size_t)i * 16 + ln];
    float sp0 = fmaxf(q0, 0.f) + log1pf(expf(-fabsf(q0))) + 1e-6f;
    float sp1 = fmaxf(q1, 0.f) + log1pf(expf(-fabsf(q1))) + 1e-6f;
    float z0 = fmaf(sp0, ep.x, o0);
    float z1 = fmaf(sp1, ep.y, o1);
    ((float2*)qz)[(size_t)i * 16 + ln] = make_float2(z0, z1);
    ((uint*)qzbf)[(size_t)i * 16 + ln] = pack2(z0, z1);
    float d0 = z0 * av4[2 * ln] + z1 * av4[2 * ln + 1];
    float d1 = z0 * av4[32 + 2 * ln] + z1 * av4[32 + 2 * ln + 1];
    for (int o = 8; o; o >>= 1) {
      d0 += __shfl_xor(d0, o, 16);
      d1 += __shfl_xor(d1, o, 16);
    }
    if (ln == 0) { el[i] = d0; er[i] = d1; }
  }
}

// ---------------- final dual-BN (64 rows/block, in-block stat reduce) ----------------
__global__ __launch_bounds__(256) void k_bn_dual(
    const float* __restrict__ xA, const float* __restrict__ sbA,
    const float* __restrict__ gA, const float* __restrict__ bA,
    const float* __restrict__ xB, const float* __restrict__ sbB,
    const float* __restrict__ gB, const float* __restrict__ bB,
    ushort* __restrict__ outbf, const float* __restrict__ av, const float* __restrict__ bv,
    float* __restrict__ el, float* __restrict__ er) {
  __shared__ float cA[96], hA[96], cB[96], hB[96];
  const int tid = threadIdx.x;
  red_scsh(sbA, gA, bA, cA, hA, tid);
  red_scsh(sbB, gB, bB, cB, hB, tid);
  __syncthreads();
  const int wv = tid >> 6;
  const int ln = tid & 63;
  for (int it = 0; it < 16; it++) {
    int w = blockIdx.x * 64 + it * 4 + wv;
    if (w >= NN) return;
    const size_t base = (size_t)w * HDIM;
    float v1 = fmaxf(fmaf(cA[ln], xA[base + ln], hA[ln]), 0.f) +
               fmaxf(fmaf(cB[ln], xB[base + ln], hB[ln]), 0.f);
    float v2 = 0.f;
    if (ln < 32) {
      int f = 64 + ln;
      v2 = fmaxf(fmaf(cA[f], xA[base + f], hA[f]), 0.f) +
           fmaxf(fmaf(cB[f], xB[base + f], hB[f]), 0.f);
    }
    outbf[base + ln] = f2b(v1);
    if (ln < 32) outbf[base + 64 + ln] = f2b(v2);
    float d0 = v1 * av[ln], d1 = v1 * bv[ln];
    if (ln < 32) { d0 = fmaf(v2, av[64 + ln], d0); d1 = fmaf(v2, bv[64 + ln], d1); }
    for (int o = 32; o > 0; o >>= 1) {
      d0 += __shfl_down(d0, o);
      d1 += __shfl_down(d1, o);
    }
    if (ln == 0) { el[w] = d0; er[w] = d1; }
  }
}

extern "C" void kernel_launch(void* const* d_in, const int* in_sizes, int n_in,
                              void* d_out, int out_size, void* d_ws, size_t ws_size,
                              hipStream_t stream) {
  const float* x    = (const float*)d_in[0];
  const int*   eidx = (const int*)d_in[1];
  const float* eps  = (const float*)d_in[2];
  const float *W[7], *Aa[7], *Bb[7];
  for (int l = 0; l < 7; l++) {
    W[l]  = (const float*)d_in[3 + 3 * l];
    Aa[l] = (const float*)d_in[4 + 3 * l];
    Bb[l] = (const float*)d_in[5 + 3 * l];
  }
  const float* bng[4] = {(const float*)d_in[24], (const float*)d_in[26],
                         (const float*)d_in[28], (const float*)d_in[30]};
  const float* bnb[4] = {(const float*)d_in[25], (const float*)d_in[27],
                         (const float*)d_in[29], (const float*)d_in[31]};

  size_t off_b = 0;
  auto alloc = [&](size_t bytes) -> void* {
    void* p = (char*)d_ws + off_b;
    off_b = (off_b + bytes + 255) & ~(size_t)255;
    return p;
  };
  ushort* hbf   = (ushort*)alloc((size_t)NN * HDIM * 2);
  ushort* sh2   = (ushort*)alloc((size_t)NN * HDIM * 2);
  float* bufB   = (float*)alloc((size_t)NN * HDIM * 4);
  float* bufD   = (float*)alloc((size_t)NN * HDIM * 4);
  ushort* qzbf  = (ushort*)alloc((size_t)NN * ZDIM * 2);
  float* el     = (float*)alloc((size_t)NN * 4);
  float* er     = (float*)alloc((size_t)NN * 4);
  float2* elp   = (float2*)alloc((size_t)NN * 8);
  float2* erp   = (float2*)alloc((size_t)NN * 8);
  int* dcnt     = (int*)alloc((size_t)NN * 4);
  const int ZCNT = EBUK + 4 * SB * 192;
  char* zregion = (char*)alloc((size_t)ZCNT * 4);
  int* bcnt     = (int*)zregion;
  float* sb0    = (float*)(bcnt + EBUK);
  float* sb1    = sb0 + SB * 192;
  float* sb2    = sb1 + SB * 192;
  float* sb3    = sb2 + SB * 192;
  ushort* srcs  = (ushort*)alloc((size_t)NN * MAXD * 2);
  uint* barr    = (uint*)alloc((size_t)EBUK * BCAP * 4);
  ushort* wt    = (ushort*)alloc((size_t)76800 * 2);
  float* avb    = (float*)alloc((size_t)256 * 4);
  (void)alloc(65536);

  float* qz    = (float*)d_out;
  float* qm    = qz + (size_t)NN * ZDIM;
  float* qs    = qm + (size_t)NN * ZDIM;
  float* recon = qs + (size_t)NN * ZDIM;

  const int SW[6] = {0, 24576, 33792, 39936, 43008, 52224};
  const float* nf = nullptr;

  PrepArgs pa;
  for (int l = 0; l < 7; l++) { pa.W[l] = W[l]; pa.a[l] = Aa[l]; }
  k_prep<<<dim3(96, 8), 256, 0, stream>>>(pa, wt, avb, bcnt, ZCNT);

  k_partA<<<CDIV(EE + NN, 2048), 256, 0, stream>>>(eidx, bcnt, barr);
  k_fatB<<<EBUK + MGRID, 256, 0, stream>>>(bcnt, barr, dcnt, srcs,
                                           x, wt + SW[0], hbf, Aa[0], el, er);

  k_agg1<96, false, true><<<CDIV(NN, 4), 256, 0, stream>>>(hbf, el, er, dcnt, srcs,
                                                           Bb[0], bufB, sb0);
  k_mfma<96, 96, 2, true, false, 1, false><<<MGRID, 256, 0, stream>>>(
      bufB, nullptr, sb0, bng[0], bnb[0], nf, nf, nf, wt + SW[1], nullptr, hbf,
      Aa[1], nullptr, el, er, nullptr, nullptr, nullptr);
  k_agg1<96, false, true><<<CDIV(NN, 4), 256, 0, stream>>>(hbf, el, er, dcnt, srcs,
                                                           Bb[1], bufD, sb1);
  k_mfma<96, 64, 3, true, false, 2, false><<<MGRID, 256, 0, stream>>>(
      bufD, bufB, sb1, bng[1], bnb[1], sb0, bng[0], bnb[0], wt + SW[2], nullptr, hbf,
      Aa[2], Aa[3], nullptr, nullptr, elp, erp, nullptr);
  k_aggmulv<<<CDIV(NN, 8), 256, 0, stream>>>(hbf, elp, erp, dcnt, srcs, Bb[2], Bb[3],
                                             qm, qs, eps, qz, qzbf, avb, el, er);

  k_agg1<32, true, false><<<CDIV(NN, 8), 256, 0, stream>>>(qzbf, el, er, dcnt, srcs,
                                                           nullptr, hbf, nullptr);
  k_mfma<32, 96, 0, false, true, 0, true><<<MGRID, 256, 0, stream>>>(
      hbf, nullptr, nf, nf, nf, nf, nf, nf, wt + SW[3], Bb[4], bufB,
      nullptr, nullptr, nullptr, nullptr, nullptr, nullptr, sb2);
  k_mfma<96, 96, 2, true, false, 1, false><<<MGRID, 256, 0, stream>>>(
      bufB, nullptr, sb2, bng[2], bnb[2], nf, nf, nf, wt + SW[4], nullptr, hbf,
      Aa[5], nullptr, el, er, nullptr, nullptr, nullptr);
  k_agg1<96, false, true><<<CDIV(NN, 4), 256, 0, stream>>>(hbf, el, er, dcnt, srcs,
                                                           Bb[5], bufD, sb3);
  k_bn_dual<<<MGRID, 256, 0, stream>>>(bufD, sb3, bng[3], bnb[3],
                                       bufB, sb2, bng[2], bnb[2],
                                       sh2, avb + 64, avb + 160, el, er);
  k_agg1<96, true, false><<<CDIV(NN, 4), 256, 0, stream>>>(sh2, el, er, dcnt, srcs,
                                                           nullptr, hbf, nullptr);
  k_mfma<96, 256, 0, false, true, 3, false><<<MGRID, 256, 0, stream>>>(
      hbf, nullptr, nf, nf, nf, nf, nf, nf, wt + SW[5], Bb[6], recon,
      nullptr, nullptr, nullptr, nullptr, nullptr, nullptr, nullptr);
}